// Round 1
// baseline (1168.742 us; speedup 1.0000x reference)
//
#include <hip/hip_runtime.h>
#include <hip/hip_bf16.h>

#define N_NODES 100000
#define N_EDGES 600000
#define N_GRAPHS 64
#define D 128

// ---------------- CSR build ----------------

__global__ void count_deg_k(const int* __restrict__ col, int* __restrict__ cnt) {
    int e = blockIdx.x * blockDim.x + threadIdx.x;
    if (e < N_EDGES) atomicAdd(&cnt[col[e]], 1);
}

__global__ __launch_bounds__(1024) void scan_k(const int* __restrict__ cnt,
                                               int* __restrict__ start) {
    __shared__ int ls[1024];
    int t = threadIdx.x;
    const int CH = (N_NODES + 1023) >> 10;  // 98
    int b = t * CH;
    int e = min(b + CH, N_NODES);
    int s = 0;
    for (int i = b; i < e; ++i) s += cnt[i];
    ls[t] = s;
    __syncthreads();
    // Hillis-Steele inclusive scan
    for (int d = 1; d < 1024; d <<= 1) {
        int v = (t >= d) ? ls[t - d] : 0;
        __syncthreads();
        ls[t] += v;
        __syncthreads();
    }
    int off = ls[t] - s;  // exclusive prefix
    for (int i = b; i < e; ++i) { start[i] = off; off += cnt[i]; }
    if (t == 1023) start[N_NODES] = ls[1023];
}

__global__ void fill_csr_k(const int* __restrict__ row, const int* __restrict__ col,
                           const int* __restrict__ start, int* __restrict__ fill,
                           int* __restrict__ esrc) {
    int e = blockIdx.x * blockDim.x + threadIdx.x;
    if (e < N_EDGES) {
        int c = col[e];
        int p = atomicAdd(&fill[c], 1);
        esrc[start[c] + p] = row[e];
    }
}

// ---------------- GEMM: out[i][j] = bias[j] + sum_k in[i][k]*W[j][k] ----------------

#define BM 128
#define BK 32

__global__ __launch_bounds__(256) void gemm_k(const float* __restrict__ A,
                                              const float* __restrict__ W,
                                              const float* __restrict__ bias,
                                              float* __restrict__ out, int nrows) {
    __shared__ float sA[BK][BM + 4];
    __shared__ float sB[BK][D + 4];
    int tid = threadIdx.x;
    int bm0 = blockIdx.x * BM;
    int tx = tid & 15, ty = tid >> 4;

    float acc[8][8];
#pragma unroll
    for (int i = 0; i < 8; ++i)
#pragma unroll
        for (int j = 0; j < 8; ++j) acc[i][j] = 0.f;

    float bv[8];
#pragma unroll
    for (int j = 0; j < 8; ++j) bv[j] = bias[tx * 8 + j];

    int lr = tid >> 3;   // 0..31
    int lc4 = tid & 7;   // float4 index within 32-float K-slab

    for (int kb = 0; kb < D; kb += BK) {
        // A tile: rows bm0 + (lr + 32*rr), cols kb + lc4*4 .. +3
#pragma unroll
        for (int rr = 0; rr < 4; ++rr) {
            int rowl = lr + rr * 32;
            int grow = bm0 + rowl;
            float4 v = make_float4(0.f, 0.f, 0.f, 0.f);
            if (grow < nrows)
                v = *reinterpret_cast<const float4*>(&A[(size_t)grow * D + kb + lc4 * 4]);
            sA[lc4 * 4 + 0][rowl] = v.x;
            sA[lc4 * 4 + 1][rowl] = v.y;
            sA[lc4 * 4 + 2][rowl] = v.z;
            sA[lc4 * 4 + 3][rowl] = v.w;
        }
        // B tile: W[j][k], j = lr + 32*rr, k = kb + lc4*4 .. +3
#pragma unroll
        for (int rr = 0; rr < 4; ++rr) {
            int j = lr + rr * 32;
            float4 v = *reinterpret_cast<const float4*>(&W[(size_t)j * D + kb + lc4 * 4]);
            sB[lc4 * 4 + 0][j] = v.x;
            sB[lc4 * 4 + 1][j] = v.y;
            sB[lc4 * 4 + 2][j] = v.z;
            sB[lc4 * 4 + 3][j] = v.w;
        }
        __syncthreads();
#pragma unroll
        for (int k = 0; k < BK; ++k) {
            float a[8], b[8];
            *reinterpret_cast<float4*>(&a[0]) = *reinterpret_cast<const float4*>(&sA[k][ty * 8]);
            *reinterpret_cast<float4*>(&a[4]) = *reinterpret_cast<const float4*>(&sA[k][ty * 8 + 4]);
            *reinterpret_cast<float4*>(&b[0]) = *reinterpret_cast<const float4*>(&sB[k][tx * 8]);
            *reinterpret_cast<float4*>(&b[4]) = *reinterpret_cast<const float4*>(&sB[k][tx * 8 + 4]);
#pragma unroll
            for (int i = 0; i < 8; ++i)
#pragma unroll
                for (int j = 0; j < 8; ++j) acc[i][j] = fmaf(a[i], b[j], acc[i][j]);
        }
        __syncthreads();
    }

#pragma unroll
    for (int i = 0; i < 8; ++i) {
        int grow = bm0 + ty * 8 + i;
        if (grow >= nrows) continue;
        float4 o0 = make_float4(acc[i][0] + bv[0], acc[i][1] + bv[1],
                                acc[i][2] + bv[2], acc[i][3] + bv[3]);
        float4 o1 = make_float4(acc[i][4] + bv[4], acc[i][5] + bv[5],
                                acc[i][6] + bv[6], acc[i][7] + bv[7]);
        *reinterpret_cast<float4*>(&out[(size_t)grow * D + tx * 8]) = o0;
        *reinterpret_cast<float4*>(&out[(size_t)grow * D + tx * 8 + 4]) = o1;
    }
}

// ---------------- Aggregation: out[i] = t[i] + sum_{e: col==i} t[src[e]] ----------------

__global__ __launch_bounds__(128) void aggregate_k(const float* __restrict__ t,
                                                   const int* __restrict__ start,
                                                   const int* __restrict__ esrc,
                                                   float* __restrict__ out, int do_relu) {
    int node = blockIdx.x;
    int d = threadIdx.x;
    int s = start[node], e = start[node + 1];
    float acc = t[(size_t)node * D + d];  // self loop
    int i = s;
    for (; i + 1 < e; i += 2) {
        int s0 = esrc[i], s1 = esrc[i + 1];
        float a = t[(size_t)s0 * D + d];
        float b = t[(size_t)s1 * D + d];
        acc += a + b;
    }
    if (i < e) acc += t[(size_t)esrc[i] * D + d];
    if (do_relu) acc = fmaxf(acc, 0.f);
    out[(size_t)node * D + d] = acc;
}

// ---------------- Pooling ----------------

__global__ __launch_bounds__(128) void pool_k(const float* __restrict__ h,
                                              const int* __restrict__ batch,
                                              float* __restrict__ pooled) {
    int d = threadIdx.x;
    int n0 = blockIdx.x * 32;
    int nend = min(n0 + 32, N_NODES);
    int curg = batch[n0];
    float acc = 0.f;
    for (int n = n0; n < nend; ++n) {
        int g = batch[n];
        if (g != curg) {
            unsafeAtomicAdd(&pooled[curg * D + d], acc);
            acc = 0.f;
            curg = g;
        }
        acc += h[(size_t)n * D + d];
    }
    unsafeAtomicAdd(&pooled[curg * D + d], acc);
}

__global__ void cnt_k(const int* __restrict__ batch, int* __restrict__ gcnt) {
    int n = blockIdx.x * blockDim.x + threadIdx.x;
    if (n < N_NODES) atomicAdd(&gcnt[batch[n]], 1);
}

__global__ __launch_bounds__(128) void final_k(const float* __restrict__ pooled,
                                               const int* __restrict__ gcnt,
                                               const float* __restrict__ Wc,
                                               const float* __restrict__ bc,
                                               float* __restrict__ out) {
    int g = blockIdx.x;
    int d = threadIdx.x;
    float c = (float)max(gcnt[g], 1);
    float v = pooled[g * D + d] / c * Wc[d];
    __shared__ float red[128];
    red[d] = v;
    __syncthreads();
    for (int s = 64; s > 0; s >>= 1) {
        if (d < s) red[d] += red[d + s];
        __syncthreads();
    }
    if (d == 0) out[g] = 1.f / (1.f + expf(-(red[0] + bc[0])));
}

// ---------------- Launch ----------------

extern "C" void kernel_launch(void* const* d_in, const int* in_sizes, int n_in,
                              void* d_out, int out_size, void* d_ws, size_t ws_size,
                              hipStream_t stream) {
    const float* x   = (const float*)d_in[0];
    const int* ei    = (const int*)d_in[1];   // [2,600000] int32
    const int* batch = (const int*)d_in[2];
    const float* W1  = (const float*)d_in[3];
    const float* b1  = (const float*)d_in[4];
    const float* W2  = (const float*)d_in[5];
    const float* b2  = (const float*)d_in[6];
    const float* W3  = (const float*)d_in[7];
    const float* b3  = (const float*)d_in[8];
    const float* W4  = (const float*)d_in[9];
    const float* b4  = (const float*)d_in[10];
    const float* Wc  = (const float*)d_in[11];
    const float* bc  = (const float*)d_in[12];
    float* out = (float*)d_out;

    const int* row = ei;             // sources
    const int* col = ei + N_EDGES;   // targets

    char* p = (char*)d_ws;
    float* t = (float*)p;      p += (size_t)N_NODES * D * 4;   // 51.2 MB
    float* h = (float*)p;      p += (size_t)N_NODES * D * 4;   // 51.2 MB
    int* esrc = (int*)p;       p += (size_t)N_EDGES * 4;       // 2.4 MB
    int* cstart = (int*)p;     p += ((N_NODES + 1) * 4 + 15) / 16 * 16;
    int* cfill = (int*)p;      p += (size_t)N_NODES * 4;
    float* pooled = (float*)p; p += N_GRAPHS * D * 4;
    int* gcnt = (int*)p;       p += 256;

    // ---- CSR build ----
    hipMemsetAsync(cfill, 0, (size_t)N_NODES * 4, stream);
    count_deg_k<<<(N_EDGES + 255) / 256, 256, 0, stream>>>(col, cfill);
    scan_k<<<1, 1024, 0, stream>>>(cfill, cstart);
    hipMemsetAsync(cfill, 0, (size_t)N_NODES * 4, stream);
    fill_csr_k<<<(N_EDGES + 255) / 256, 256, 0, stream>>>(row, col, cstart, cfill, esrc);

    const int ggrid = (N_NODES + BM - 1) / BM;  // 782

    // ---- Layer 1 ----
    gemm_k<<<ggrid, 256, 0, stream>>>(x, W1, b1, t, N_NODES);
    aggregate_k<<<N_NODES, 128, 0, stream>>>(t, cstart, esrc, h, 1);
    // ---- Layer 2 ----
    gemm_k<<<ggrid, 256, 0, stream>>>(h, W2, b2, t, N_NODES);
    aggregate_k<<<N_NODES, 128, 0, stream>>>(t, cstart, esrc, h, 1);
    // ---- Layer 3 ----
    gemm_k<<<ggrid, 256, 0, stream>>>(h, W3, b3, t, N_NODES);
    aggregate_k<<<N_NODES, 128, 0, stream>>>(t, cstart, esrc, h, 1);
    // ---- Layer 4 ----
    gemm_k<<<ggrid, 256, 0, stream>>>(h, W4, b4, t, N_NODES);
    aggregate_k<<<N_NODES, 128, 0, stream>>>(t, cstart, esrc, h, 0);

    // ---- Pooling + head ----
    hipMemsetAsync(pooled, 0, (size_t)N_GRAPHS * D * 4 + 256, stream);
    pool_k<<<(N_NODES + 31) / 32, 128, 0, stream>>>(h, batch, pooled);
    cnt_k<<<(N_NODES + 1023) / 1024, 1024, 0, stream>>>(batch, gcnt);
    final_k<<<N_GRAPHS, 128, 0, stream>>>(pooled, gcnt, Wc, bc, out);
}

// Round 2
// 728.004 us; speedup vs baseline: 1.6054x; 1.6054x over previous
//
#include <hip/hip_runtime.h>
#include <hip/hip_bf16.h>

#define N_NODES 100000
#define N_EDGES 600000
#define N_GRAPHS 64
#define D 128

// ---------------- CSR build ----------------

__global__ void count_deg_k(const int* __restrict__ col, int* __restrict__ cnt) {
    int e = blockIdx.x * blockDim.x + threadIdx.x;
    if (e < N_EDGES) atomicAdd(&cnt[col[e]], 1);
}

__global__ __launch_bounds__(1024) void scan_k(const int* __restrict__ cnt,
                                               int* __restrict__ start) {
    __shared__ int ls[1024];
    int t = threadIdx.x;
    const int CH = (N_NODES + 1023) >> 10;  // 98
    int b = t * CH;
    int e = min(b + CH, N_NODES);
    int s = 0;
    for (int i = b; i < e; ++i) s += cnt[i];
    ls[t] = s;
    __syncthreads();
    // Hillis-Steele inclusive scan
    for (int d = 1; d < 1024; d <<= 1) {
        int v = (t >= d) ? ls[t - d] : 0;
        __syncthreads();
        ls[t] += v;
        __syncthreads();
    }
    int off = ls[t] - s;  // exclusive prefix
    for (int i = b; i < e; ++i) { start[i] = off; off += cnt[i]; }
    if (t == 1023) start[N_NODES] = ls[1023];
}

__global__ void fill_csr_k(const int* __restrict__ row, const int* __restrict__ col,
                           const int* __restrict__ start, int* __restrict__ fill,
                           int* __restrict__ esrc) {
    int e = blockIdx.x * blockDim.x + threadIdx.x;
    if (e < N_EDGES) {
        int c = col[e];
        int p = atomicAdd(&fill[c], 1);
        esrc[start[c] + p] = row[e];
    }
}

// ---------------- graph segment bounds (batch is sorted) ----------------

__global__ __launch_bounds__(128) void bounds_k(const int* __restrict__ batch,
                                                int* __restrict__ gstart) {
    int g = threadIdx.x;
    if (g > N_GRAPHS) return;
    int lo = 0, hi = N_NODES;
    while (lo < hi) {
        int mid = (lo + hi) >> 1;
        if (batch[mid] < g) lo = mid + 1; else hi = mid;
    }
    gstart[g] = lo;
}

// ---------------- GEMM: out[i][j] = bias[j] + sum_k in[i][k]*W[j][k] ----------------

#define BM 128
#define BK 32

__global__ __launch_bounds__(256) void gemm_k(const float* __restrict__ A,
                                              const float* __restrict__ W,
                                              const float* __restrict__ bias,
                                              float* __restrict__ out, int nrows) {
    __shared__ float sA[BK][BM + 4];
    __shared__ float sB[BK][D + 4];
    int tid = threadIdx.x;
    int bm0 = blockIdx.x * BM;
    int tx = tid & 15, ty = tid >> 4;

    float acc[8][8];
#pragma unroll
    for (int i = 0; i < 8; ++i)
#pragma unroll
        for (int j = 0; j < 8; ++j) acc[i][j] = 0.f;

    float bv[8];
#pragma unroll
    for (int j = 0; j < 8; ++j) bv[j] = bias[tx * 8 + j];

    int lr = tid >> 3;   // 0..31
    int lc4 = tid & 7;   // float4 index within 32-float K-slab

    for (int kb = 0; kb < D; kb += BK) {
#pragma unroll
        for (int rr = 0; rr < 4; ++rr) {
            int rowl = lr + rr * 32;
            int grow = bm0 + rowl;
            float4 v = make_float4(0.f, 0.f, 0.f, 0.f);
            if (grow < nrows)
                v = *reinterpret_cast<const float4*>(&A[(size_t)grow * D + kb + lc4 * 4]);
            sA[lc4 * 4 + 0][rowl] = v.x;
            sA[lc4 * 4 + 1][rowl] = v.y;
            sA[lc4 * 4 + 2][rowl] = v.z;
            sA[lc4 * 4 + 3][rowl] = v.w;
        }
#pragma unroll
        for (int rr = 0; rr < 4; ++rr) {
            int j = lr + rr * 32;
            float4 v = *reinterpret_cast<const float4*>(&W[(size_t)j * D + kb + lc4 * 4]);
            sB[lc4 * 4 + 0][j] = v.x;
            sB[lc4 * 4 + 1][j] = v.y;
            sB[lc4 * 4 + 2][j] = v.z;
            sB[lc4 * 4 + 3][j] = v.w;
        }
        __syncthreads();
#pragma unroll
        for (int k = 0; k < BK; ++k) {
            float a[8], b[8];
            *reinterpret_cast<float4*>(&a[0]) = *reinterpret_cast<const float4*>(&sA[k][ty * 8]);
            *reinterpret_cast<float4*>(&a[4]) = *reinterpret_cast<const float4*>(&sA[k][ty * 8 + 4]);
            *reinterpret_cast<float4*>(&b[0]) = *reinterpret_cast<const float4*>(&sB[k][tx * 8]);
            *reinterpret_cast<float4*>(&b[4]) = *reinterpret_cast<const float4*>(&sB[k][tx * 8 + 4]);
#pragma unroll
            for (int i = 0; i < 8; ++i)
#pragma unroll
                for (int j = 0; j < 8; ++j) acc[i][j] = fmaf(a[i], b[j], acc[i][j]);
        }
        __syncthreads();
    }

#pragma unroll
    for (int i = 0; i < 8; ++i) {
        int grow = bm0 + ty * 8 + i;
        if (grow >= nrows) continue;
        float4 o0 = make_float4(acc[i][0] + bv[0], acc[i][1] + bv[1],
                                acc[i][2] + bv[2], acc[i][3] + bv[3]);
        float4 o1 = make_float4(acc[i][4] + bv[4], acc[i][5] + bv[5],
                                acc[i][6] + bv[6], acc[i][7] + bv[7]);
        *reinterpret_cast<float4*>(&out[(size_t)grow * D + tx * 8]) = o0;
        *reinterpret_cast<float4*>(&out[(size_t)grow * D + tx * 8 + 4]) = o1;
    }
}

// ---------------- Aggregation: out[i] = t[i] + sum_{e: col==i} t[src[e]] ----------------

__global__ __launch_bounds__(128) void aggregate_k(const float* __restrict__ t,
                                                   const int* __restrict__ start,
                                                   const int* __restrict__ esrc,
                                                   float* __restrict__ out, int do_relu) {
    int node = blockIdx.x;
    int d = threadIdx.x;
    int s = start[node], e = start[node + 1];
    float acc = t[(size_t)node * D + d];  // self loop
    int i = s;
    for (; i + 1 < e; i += 2) {
        int s0 = esrc[i], s1 = esrc[i + 1];
        float a = t[(size_t)s0 * D + d];
        float b = t[(size_t)s1 * D + d];
        acc += a + b;
    }
    if (i < e) acc += t[(size_t)esrc[i] * D + d];
    if (do_relu) acc = fmaxf(acc, 0.f);
    out[(size_t)node * D + d] = acc;
}

// ---------------- Pooling ----------------

__global__ __launch_bounds__(128) void pool_k(const float* __restrict__ h,
                                              const int* __restrict__ batch,
                                              float* __restrict__ pooled) {
    int d = threadIdx.x;
    int n0 = blockIdx.x * 32;
    int nend = min(n0 + 32, N_NODES);
    int curg = batch[n0];
    float acc = 0.f;
    for (int n = n0; n < nend; ++n) {
        int g = batch[n];
        if (g != curg) {
            unsafeAtomicAdd(&pooled[curg * D + d], acc);
            acc = 0.f;
            curg = g;
        }
        acc += h[(size_t)n * D + d];
    }
    unsafeAtomicAdd(&pooled[curg * D + d], acc);
}

__global__ __launch_bounds__(128) void final_k(const float* __restrict__ pooled,
                                               const int* __restrict__ gstart,
                                               const float* __restrict__ Wc,
                                               const float* __restrict__ bc,
                                               float* __restrict__ out) {
    int g = blockIdx.x;
    int d = threadIdx.x;
    float c = (float)max(gstart[g + 1] - gstart[g], 1);
    float v = pooled[g * D + d] / c * Wc[d];
    __shared__ float red[128];
    red[d] = v;
    __syncthreads();
    for (int s = 64; s > 0; s >>= 1) {
        if (d < s) red[d] += red[d + s];
        __syncthreads();
    }
    if (d == 0) out[g] = 1.f / (1.f + expf(-(red[0] + bc[0])));
}

// ---------------- Launch ----------------

extern "C" void kernel_launch(void* const* d_in, const int* in_sizes, int n_in,
                              void* d_out, int out_size, void* d_ws, size_t ws_size,
                              hipStream_t stream) {
    const float* x   = (const float*)d_in[0];
    const int* ei    = (const int*)d_in[1];   // [2,600000] int32
    const int* batch = (const int*)d_in[2];
    const float* W1  = (const float*)d_in[3];
    const float* b1  = (const float*)d_in[4];
    const float* W2  = (const float*)d_in[5];
    const float* b2  = (const float*)d_in[6];
    const float* W3  = (const float*)d_in[7];
    const float* b3  = (const float*)d_in[8];
    const float* W4  = (const float*)d_in[9];
    const float* b4  = (const float*)d_in[10];
    const float* Wc  = (const float*)d_in[11];
    const float* bc  = (const float*)d_in[12];
    float* out = (float*)d_out;

    const int* row = ei;             // sources
    const int* col = ei + N_EDGES;   // targets

    char* p = (char*)d_ws;
    float* t = (float*)p;      p += (size_t)N_NODES * D * 4;   // 51.2 MB
    float* h = (float*)p;      p += (size_t)N_NODES * D * 4;   // 51.2 MB
    int* esrc = (int*)p;       p += (size_t)N_EDGES * 4;       // 2.4 MB
    int* cstart = (int*)p;     p += ((N_NODES + 1) * 4 + 15) / 16 * 16;
    int* cfill = (int*)p;      p += (size_t)N_NODES * 4;
    float* pooled = (float*)p; p += N_GRAPHS * D * 4;
    int* gstart = (int*)p;     p += 256;

    // ---- CSR build ----
    hipMemsetAsync(cfill, 0, (size_t)N_NODES * 4, stream);
    count_deg_k<<<(N_EDGES + 255) / 256, 256, 0, stream>>>(col, cfill);
    scan_k<<<1, 1024, 0, stream>>>(cfill, cstart);
    hipMemsetAsync(cfill, 0, (size_t)N_NODES * 4, stream);
    fill_csr_k<<<(N_EDGES + 255) / 256, 256, 0, stream>>>(row, col, cstart, cfill, esrc);

    // ---- graph bounds (replaces 446us atomic histogram) ----
    bounds_k<<<1, 128, 0, stream>>>(batch, gstart);

    const int ggrid = (N_NODES + BM - 1) / BM;  // 782

    // ---- Layer 1 ----
    gemm_k<<<ggrid, 256, 0, stream>>>(x, W1, b1, t, N_NODES);
    aggregate_k<<<N_NODES, 128, 0, stream>>>(t, cstart, esrc, h, 1);
    // ---- Layer 2 ----
    gemm_k<<<ggrid, 256, 0, stream>>>(h, W2, b2, t, N_NODES);
    aggregate_k<<<N_NODES, 128, 0, stream>>>(t, cstart, esrc, h, 1);
    // ---- Layer 3 ----
    gemm_k<<<ggrid, 256, 0, stream>>>(h, W3, b3, t, N_NODES);
    aggregate_k<<<N_NODES, 128, 0, stream>>>(t, cstart, esrc, h, 1);
    // ---- Layer 4 ----
    gemm_k<<<ggrid, 256, 0, stream>>>(h, W4, b4, t, N_NODES);
    aggregate_k<<<N_NODES, 128, 0, stream>>>(t, cstart, esrc, h, 0);

    // ---- Pooling + head ----
    hipMemsetAsync(pooled, 0, (size_t)N_GRAPHS * D * 4, stream);
    pool_k<<<(N_NODES + 31) / 32, 128, 0, stream>>>(h, batch, pooled);
    final_k<<<N_GRAPHS, 128, 0, stream>>>(pooled, gstart, Wc, bc, out);
}

// Round 3
// 579.589 us; speedup vs baseline: 2.0165x; 1.2561x over previous
//
#include <hip/hip_runtime.h>
#include <hip/hip_bf16.h>

#define N_NODES 100000
#define N_EDGES 600000
#define N_GRAPHS 64
#define D 128

#define NBLK_SCAN ((N_NODES + 255) / 256)  // 391

// ---------------- CSR build ----------------

__global__ void count_deg_k(const int* __restrict__ col, int* __restrict__ cnt) {
    int e = blockIdx.x * blockDim.x + threadIdx.x;
    if (e < N_EDGES) atomicAdd(&cnt[col[e]], 1);
}

// per-block reduce of 256 counts
__global__ __launch_bounds__(256) void partial_k(const int* __restrict__ cnt,
                                                 int* __restrict__ psum) {
    int i = blockIdx.x * 256 + threadIdx.x;
    int v = (i < N_NODES) ? cnt[i] : 0;
#pragma unroll
    for (int d = 32; d > 0; d >>= 1) v += __shfl_down(v, d, 64);
    __shared__ int ws[4];
    if ((threadIdx.x & 63) == 0) ws[threadIdx.x >> 6] = v;
    __syncthreads();
    if (threadIdx.x == 0) psum[blockIdx.x] = ws[0] + ws[1] + ws[2] + ws[3];
}

// single-block exclusive scan of the 391 block sums
__global__ __launch_bounds__(512) void scanpart_k(int* __restrict__ psum) {
    __shared__ int ls[512];
    int t = threadIdx.x;
    int v = (t < NBLK_SCAN) ? psum[t] : 0;
    ls[t] = v;
    __syncthreads();
    for (int d = 1; d < 512; d <<= 1) {
        int u = (t >= d) ? ls[t - d] : 0;
        __syncthreads();
        ls[t] += u;
        __syncthreads();
    }
    if (t < NBLK_SCAN) psum[t] = ls[t] - v;  // exclusive
}

// per-block scan of 256 counts + block offset -> start[]
__global__ __launch_bounds__(256) void scan_scatter_k(const int* __restrict__ cnt,
                                                      const int* __restrict__ psum,
                                                      int* __restrict__ start) {
    int b = blockIdx.x, t = threadIdx.x;
    int i = b * 256 + t;
    int v = (i < N_NODES) ? cnt[i] : 0;
    __shared__ int ls[256];
    ls[t] = v;
    __syncthreads();
    for (int d = 1; d < 256; d <<= 1) {
        int u = (t >= d) ? ls[t - d] : 0;
        __syncthreads();
        ls[t] += u;
        __syncthreads();
    }
    int incl = ls[t];
    int off = psum[b];
    if (i < N_NODES) start[i] = off + incl - v;
    if (i == N_NODES - 1) start[N_NODES] = off + incl;
}

__global__ void fill_csr_k(const int* __restrict__ row, const int* __restrict__ col,
                           const int* __restrict__ start, int* __restrict__ fill,
                           int* __restrict__ esrc) {
    int e = blockIdx.x * blockDim.x + threadIdx.x;
    if (e < N_EDGES) {
        int c = col[e];
        int p = atomicAdd(&fill[c], 1);
        esrc[start[c] + p] = row[e];
    }
}

// ---------------- graph segment bounds (batch is sorted) ----------------

__global__ __launch_bounds__(128) void bounds_k(const int* __restrict__ batch,
                                                int* __restrict__ gstart) {
    int g = threadIdx.x;
    if (g > N_GRAPHS) return;
    int lo = 0, hi = N_NODES;
    while (lo < hi) {
        int mid = (lo + hi) >> 1;
        if (batch[mid] < g) lo = mid + 1; else hi = mid;
    }
    gstart[g] = lo;
}

// ---------------- GEMM: out[i][j] = bias[j] + sum_k in[i][k]*W[j][k] ----------------

#define BM 128
#define BK 32

__global__ __launch_bounds__(256) void gemm_k(const float* __restrict__ A,
                                              const float* __restrict__ W,
                                              const float* __restrict__ bias,
                                              float* __restrict__ out, int nrows) {
    __shared__ float sA[BK][BM + 4];
    __shared__ float sB[BK][D + 4];
    int tid = threadIdx.x;
    int bm0 = blockIdx.x * BM;
    int tx = tid & 15, ty = tid >> 4;

    float acc[8][8];
#pragma unroll
    for (int i = 0; i < 8; ++i)
#pragma unroll
        for (int j = 0; j < 8; ++j) acc[i][j] = 0.f;

    float bv[8];
#pragma unroll
    for (int j = 0; j < 8; ++j) bv[j] = bias[tx * 8 + j];

    int lr = tid >> 3;   // 0..31
    int lc4 = tid & 7;   // float4 index within 32-float K-slab

    for (int kb = 0; kb < D; kb += BK) {
#pragma unroll
        for (int rr = 0; rr < 4; ++rr) {
            int rowl = lr + rr * 32;
            int grow = bm0 + rowl;
            float4 v = make_float4(0.f, 0.f, 0.f, 0.f);
            if (grow < nrows)
                v = *reinterpret_cast<const float4*>(&A[(size_t)grow * D + kb + lc4 * 4]);
            sA[lc4 * 4 + 0][rowl] = v.x;
            sA[lc4 * 4 + 1][rowl] = v.y;
            sA[lc4 * 4 + 2][rowl] = v.z;
            sA[lc4 * 4 + 3][rowl] = v.w;
        }
#pragma unroll
        for (int rr = 0; rr < 4; ++rr) {
            int j = lr + rr * 32;
            float4 v = *reinterpret_cast<const float4*>(&W[(size_t)j * D + kb + lc4 * 4]);
            sB[lc4 * 4 + 0][j] = v.x;
            sB[lc4 * 4 + 1][j] = v.y;
            sB[lc4 * 4 + 2][j] = v.z;
            sB[lc4 * 4 + 3][j] = v.w;
        }
        __syncthreads();
#pragma unroll
        for (int k = 0; k < BK; ++k) {
            float a[8], b[8];
            *reinterpret_cast<float4*>(&a[0]) = *reinterpret_cast<const float4*>(&sA[k][ty * 8]);
            *reinterpret_cast<float4*>(&a[4]) = *reinterpret_cast<const float4*>(&sA[k][ty * 8 + 4]);
            *reinterpret_cast<float4*>(&b[0]) = *reinterpret_cast<const float4*>(&sB[k][tx * 8]);
            *reinterpret_cast<float4*>(&b[4]) = *reinterpret_cast<const float4*>(&sB[k][tx * 8 + 4]);
#pragma unroll
            for (int i = 0; i < 8; ++i)
#pragma unroll
                for (int j = 0; j < 8; ++j) acc[i][j] = fmaf(a[i], b[j], acc[i][j]);
        }
        __syncthreads();
    }

#pragma unroll
    for (int i = 0; i < 8; ++i) {
        int grow = bm0 + ty * 8 + i;
        if (grow >= nrows) continue;
        float4 o0 = make_float4(acc[i][0] + bv[0], acc[i][1] + bv[1],
                                acc[i][2] + bv[2], acc[i][3] + bv[3]);
        float4 o1 = make_float4(acc[i][4] + bv[4], acc[i][5] + bv[5],
                                acc[i][6] + bv[6], acc[i][7] + bv[7]);
        *reinterpret_cast<float4*>(&out[(size_t)grow * D + tx * 8]) = o0;
        *reinterpret_cast<float4*>(&out[(size_t)grow * D + tx * 8 + 4]) = o1;
    }
}

// ---------------- Aggregation: out[i] = t[i] + sum_{e: col==i} t[src[e]] ----------------

__global__ __launch_bounds__(128) void aggregate_k(const float* __restrict__ t,
                                                   const int* __restrict__ start,
                                                   const int* __restrict__ esrc,
                                                   float* __restrict__ out, int do_relu) {
    int node = blockIdx.x;
    int d = threadIdx.x;
    int s = start[node], e = start[node + 1];
    float acc = t[(size_t)node * D + d];  // self loop
    int i = s;
    for (; i + 1 < e; i += 2) {
        int s0 = esrc[i], s1 = esrc[i + 1];
        float a = t[(size_t)s0 * D + d];
        float b = t[(size_t)s1 * D + d];
        acc += a + b;
    }
    if (i < e) acc += t[(size_t)esrc[i] * D + d];
    if (do_relu) acc = fmaxf(acc, 0.f);
    out[(size_t)node * D + d] = acc;
}

// ---------------- Pooling ----------------

__global__ __launch_bounds__(128) void pool_k(const float* __restrict__ h,
                                              const int* __restrict__ batch,
                                              float* __restrict__ pooled) {
    int d = threadIdx.x;
    int n0 = blockIdx.x * 32;
    int nend = min(n0 + 32, N_NODES);
    int curg = batch[n0];
    float acc = 0.f;
    for (int n = n0; n < nend; ++n) {
        int g = batch[n];
        if (g != curg) {
            unsafeAtomicAdd(&pooled[curg * D + d], acc);
            acc = 0.f;
            curg = g;
        }
        acc += h[(size_t)n * D + d];
    }
    unsafeAtomicAdd(&pooled[curg * D + d], acc);
}

__global__ __launch_bounds__(128) void final_k(const float* __restrict__ pooled,
                                               const int* __restrict__ gstart,
                                               const float* __restrict__ Wc,
                                               const float* __restrict__ bc,
                                               float* __restrict__ out) {
    int g = blockIdx.x;
    int d = threadIdx.x;
    float c = (float)max(gstart[g + 1] - gstart[g], 1);
    float v = pooled[g * D + d] / c * Wc[d];
    __shared__ float red[128];
    red[d] = v;
    __syncthreads();
    for (int s = 64; s > 0; s >>= 1) {
        if (d < s) red[d] += red[d + s];
        __syncthreads();
    }
    if (d == 0) out[g] = 1.f / (1.f + expf(-(red[0] + bc[0])));
}

// ---------------- Launch ----------------

extern "C" void kernel_launch(void* const* d_in, const int* in_sizes, int n_in,
                              void* d_out, int out_size, void* d_ws, size_t ws_size,
                              hipStream_t stream) {
    const float* x   = (const float*)d_in[0];
    const int* ei    = (const int*)d_in[1];   // [2,600000] int32
    const int* batch = (const int*)d_in[2];
    const float* W1  = (const float*)d_in[3];
    const float* b1  = (const float*)d_in[4];
    const float* W2  = (const float*)d_in[5];
    const float* b2  = (const float*)d_in[6];
    const float* W3  = (const float*)d_in[7];
    const float* b3  = (const float*)d_in[8];
    const float* W4  = (const float*)d_in[9];
    const float* b4  = (const float*)d_in[10];
    const float* Wc  = (const float*)d_in[11];
    const float* bc  = (const float*)d_in[12];
    float* out = (float*)d_out;

    const int* row = ei;             // sources
    const int* col = ei + N_EDGES;   // targets

    char* p = (char*)d_ws;
    float* t = (float*)p;      p += (size_t)N_NODES * D * 4;   // 51.2 MB
    float* h = (float*)p;      p += (size_t)N_NODES * D * 4;   // 51.2 MB
    int* esrc = (int*)p;       p += (size_t)N_EDGES * 4;       // 2.4 MB
    int* cstart = (int*)p;     p += ((N_NODES + 1) * 4 + 15) / 16 * 16;
    int* cfill = (int*)p;      p += (size_t)N_NODES * 4;
    int* psum = (int*)p;       p += ((NBLK_SCAN + 3) / 4) * 16;
    float* pooled = (float*)p; p += N_GRAPHS * D * 4;
    int* gstart = (int*)p;     p += 256;

    // ---- CSR build ----
    hipMemsetAsync(cfill, 0, (size_t)N_NODES * 4, stream);
    count_deg_k<<<(N_EDGES + 255) / 256, 256, 0, stream>>>(col, cfill);
    partial_k<<<NBLK_SCAN, 256, 0, stream>>>(cfill, psum);
    scanpart_k<<<1, 512, 0, stream>>>(psum);
    scan_scatter_k<<<NBLK_SCAN, 256, 0, stream>>>(cfill, psum, cstart);
    hipMemsetAsync(cfill, 0, (size_t)N_NODES * 4, stream);
    fill_csr_k<<<(N_EDGES + 255) / 256, 256, 0, stream>>>(row, col, cstart, cfill, esrc);

    // ---- graph bounds ----
    bounds_k<<<1, 128, 0, stream>>>(batch, gstart);

    const int ggrid = (N_NODES + BM - 1) / BM;  // 782

    // ---- Layer 1 ----
    gemm_k<<<ggrid, 256, 0, stream>>>(x, W1, b1, t, N_NODES);
    aggregate_k<<<N_NODES, 128, 0, stream>>>(t, cstart, esrc, h, 1);
    // ---- Layer 2 ----
    gemm_k<<<ggrid, 256, 0, stream>>>(h, W2, b2, t, N_NODES);
    aggregate_k<<<N_NODES, 128, 0, stream>>>(t, cstart, esrc, h, 1);
    // ---- Layer 3 ----
    gemm_k<<<ggrid, 256, 0, stream>>>(h, W3, b3, t, N_NODES);
    aggregate_k<<<N_NODES, 128, 0, stream>>>(t, cstart, esrc, h, 1);
    // ---- Layer 4 ----
    gemm_k<<<ggrid, 256, 0, stream>>>(h, W4, b4, t, N_NODES);
    aggregate_k<<<N_NODES, 128, 0, stream>>>(t, cstart, esrc, h, 0);

    // ---- Pooling + head ----
    hipMemsetAsync(pooled, 0, (size_t)N_GRAPHS * D * 4, stream);
    pool_k<<<(N_NODES + 31) / 32, 128, 0, stream>>>(h, batch, pooled);
    final_k<<<N_GRAPHS, 128, 0, stream>>>(pooled, gstart, Wc, bc, out);
}